// Round 4
// baseline (213.002 us; speedup 1.0000x reference)
//
#include <hip/hip_runtime.h>
#include <cstdint>

// MultiHeadAttention: B=2 S=2048 D=768 H=12 dk=64, fp32 in/out, bf16 MFMA inside.
//
//   convert_all : q,k,v,w_q,w_k,w_v,w_o fp32 -> bf16              (ws)
//   qkv         : m97-style GEMM: global_load_lds width-16 DMA staging,
//                 single-buffered LDS, 2 barriers/iter, 128x128 tile.
//   attn        : flash attention (no-max softmax), 32x32x16 MFMA, in-reg P.
//                 R4: V direct-to-REGISTER from global with one-full-phase
//                 prefetch distance (R1 failed because V loads sat INSIDE the
//                 step with zero lead; R0's reg-staging proved a full-phase
//                 lead hides L2 latency). K stays LDS-staged (shared by both
//                 rh-waves -> 2x dedup). LDS insts/block-phase 96 -> 48;
//                 V-side conflicts and fetch/store VALU deleted.
//   o           : 64x128-tile DMA GEMM -> fp32 d_out

#define S_LEN 2048
#define NHEAD 12
#define DMODEL 768

typedef short s16x8 __attribute__((ext_vector_type(8)));
typedef float f32x4 __attribute__((ext_vector_type(4)));
typedef float f32x16 __attribute__((ext_vector_type(16)));

#define MFMA16(a, b, c) __builtin_amdgcn_mfma_f32_16x16x32_bf16((a), (b), (c), 0, 0, 0)
#define MFMA32(a, b, c) __builtin_amdgcn_mfma_f32_32x32x16_bf16((a), (b), (c), 0, 0, 0)

__device__ __forceinline__ void lds_dma16(void* lds, const void* g) {
  __builtin_amdgcn_global_load_lds(
      (const __attribute__((address_space(1))) unsigned int*)g,
      (__attribute__((address_space(3))) unsigned int*)lds, 16, 0, 0);
}

__device__ __forceinline__ unsigned int pk_bf16(float a, float b) {
  unsigned int ua = __float_as_uint(a), ub = __float_as_uint(b);
  ua = (ua + 0x7FFFu + ((ua >> 16) & 1u)) >> 16;   // RNE
  ub = (ub + 0x7FFFu + ((ub >> 16) & 1u)) >> 16;
  return ua | (ub << 16);
}
__device__ __forceinline__ short bf16r(float a) {
  unsigned int ua = __float_as_uint(a);
  return (short)((ua + 0x7FFFu + ((ua >> 16) & 1u)) >> 16);
}
// pack hi16(b)<<16 | hi16(a) in ONE v_perm_b32 (trunc; bias cancelled via l)
__device__ __forceinline__ unsigned int pk_trunc(float a, float b) {
  return __builtin_amdgcn_perm(__float_as_uint(b), __float_as_uint(a), 0x07060302u);
}
__device__ __forceinline__ float bf16_floor(float a) {
  return __uint_as_float(__float_as_uint(a) & 0xFFFF0000u);
}

// ---------------------------------------------------------------------------
// All fp32 -> bf16 conversions in ONE launch. 11520 blocks x 256 thr x
// float4/thr: blocks [0,9216) = q,k,v (3072 each); [9216,11520) = 4 weights
// (576 each).
// ---------------------------------------------------------------------------
__global__ __launch_bounds__(256)
void convert_all(const float* __restrict__ q, const float* __restrict__ k,
                 const float* __restrict__ v,
                 const float* __restrict__ w0, const float* __restrict__ w1,
                 const float* __restrict__ w2, const float* __restrict__ w3,
                 short* __restrict__ qb, short* __restrict__ kb,
                 short* __restrict__ vb,
                 short* __restrict__ o0, short* __restrict__ o1,
                 short* __restrict__ o2, short* __restrict__ o3) {
  int b = blockIdx.x;
  const float* src;
  short* dst;
  if (b < 9216) {
    const int s = b / 3072;
    src = (s == 0) ? q : (s == 1) ? k : v;
    dst = (s == 0) ? qb : (s == 1) ? kb : vb;
    b -= s * 3072;
  } else {
    b -= 9216;
    const int s = b / 576;
    src = (s == 0) ? w0 : (s == 1) ? w1 : (s == 2) ? w2 : w3;
    dst = (s == 0) ? o0 : (s == 1) ? o1 : (s == 2) ? o2 : o3;
    b -= s * 576;
  }
  const long i = ((long)b * 256 + threadIdx.x) * 4;
  float4 f = *(const float4*)(src + i);
  uint2 u;
  u.x = pk_bf16(f.x, f.y);
  u.y = pk_bf16(f.z, f.w);
  *(uint2*)(dst + i) = u;
}

// ---------------------------------------------------------------------------
// Fused QKV projection, m97-style. 576 blocks, XCD-swizzled.
// Tile 128x128, BK=32, 4 waves each 64x64 (acc[4][4]).
// Staging: global_load_lds x4 per wave (A 2, B 2), LDS rows of 32 shorts.
// ---------------------------------------------------------------------------
__global__ __launch_bounds__(256)
void qkv_kernel(const short* __restrict__ qb, const short* __restrict__ kb,
                const short* __restrict__ vb,
                const short* __restrict__ wq, const short* __restrict__ wk,
                const short* __restrict__ wv,
                const float* __restrict__ bq, const float* __restrict__ bk,
                const float* __restrict__ bv,
                short* __restrict__ qh, short* __restrict__ kh,
                short* __restrict__ vt) {
  constexpr int K = 768;
  __shared__ short Abuf[128 * 32];   // [row][k], 64B rows
  __shared__ short Bbuf[128 * 32];

  const int L   = blockIdx.x;        // 0..575
  const int xcd = L & 7;
  const int i   = L >> 3;            // 0..71
  const int nt  = i % 6;
  const int pl  = xcd * 12 + i / 6;  // 0..95 (m,z) pair
  const int z   = pl >> 5;           // 32 m-tiles per z
  const int mt  = pl & 31;
  const int m0  = mt * 128;          // token
  const int n0  = nt * 128;          // feature

  const short* A = (z == 0) ? qb : (z == 1) ? kb : vb;
  const short* B = (z == 0) ? wq : (z == 1) ? wk : wv;
  const float* bias = (z == 0) ? bq : (z == 1) ? bk : bv;

  const int tid  = threadIdx.x;
  const int lane = tid & 63;
  const int w    = tid >> 6;
  const int g    = lane >> 4;
  const int c    = lane & 15;
  const int wm   = (w & 1) * 64;
  const int wn   = (w >> 1) * 64;

  // DMA addressing: wave w covers rows [w*32, w*32+32), 2 insts x 16 rows.
  // lane l -> row +l/4, col (l&3)*8; LDS linear dest = base + l*16B.
  const int drow = w * 32 + (lane >> 2);
  const int dcol = (lane & 3) * 8;
  const short* Ag = A + (long)(m0 + drow) * K + dcol;
  const short* Bg = B + (long)(n0 + drow) * K + dcol;
  short* Al0 = &Abuf[w * 1024];
  short* Al1 = &Abuf[w * 1024 + 512];
  short* Bl0 = &Bbuf[w * 1024];
  short* Bl1 = &Bbuf[w * 1024 + 512];

  f32x4 acc[4][4];
#pragma unroll
  for (int a = 0; a < 4; ++a)
#pragma unroll
    for (int b2 = 0; b2 < 4; ++b2) acc[a][b2] = (f32x4){0.f, 0.f, 0.f, 0.f};

  for (int kt = 0; kt < K; kt += 32) {
    lds_dma16(Al0, Ag + kt);
    lds_dma16(Al1, Ag + (long)16 * K + kt);
    lds_dma16(Bl0, Bg + kt);
    lds_dma16(Bl1, Bg + (long)16 * K + kt);
    __syncthreads();   // vmcnt(0) drain: DMA landed

    s16x8 af[4], bf[4];
#pragma unroll
    for (int mb = 0; mb < 4; ++mb)
      af[mb] = *(const s16x8*)&Abuf[(wm + mb * 16 + c) * 32 + g * 8];
#pragma unroll
    for (int nb = 0; nb < 4; ++nb)
      bf[nb] = *(const s16x8*)&Bbuf[(wn + nb * 16 + c) * 32 + g * 8];
#pragma unroll
    for (int mb = 0; mb < 4; ++mb)
#pragma unroll
      for (int nb = 0; nb < 4; ++nb)
        acc[mb][nb] = MFMA16(af[mb], bf[nb], acc[mb][nb]);
    __syncthreads();   // safe to overwrite LDS
  }

  if (z < 2) {
    short* outp = z ? kh : qh;
    const float scale = z ? 1.0f : 0.18033688011112042f;  // log2e/8
#pragma unroll
    for (int mb = 0; mb < 4; ++mb) {
#pragma unroll
      for (int nb = 0; nb < 4; ++nb) {
        const int n = n0 + wn + nb * 16 + c;
        const float bvv = bias[n];
        const int hh = n >> 6, d = n & 63;
#pragma unroll
        for (int r = 0; r < 4; ++r) {
          const int m = m0 + wm + mb * 16 + g * 4 + r;
          const int b2 = m >> 11, s = m & 2047;
          const float val = (acc[mb][nb][r] + bvv) * scale;
          outp[(((long)(b2 * NHEAD + hh) * S_LEN + s) << 6) + d] = bf16r(val);
        }
      }
    }
  } else {  // V: transposed write Vt[b][h][d][t], 4 consecutive t per lane
#pragma unroll
    for (int mb = 0; mb < 4; ++mb) {
#pragma unroll
      for (int nb = 0; nb < 4; ++nb) {
        const int n = n0 + wn + nb * 16 + c;   // feature
        const float bvv = bias[n];
        const int hh = n >> 6, d = n & 63;
        const int m_base = m0 + wm + mb * 16 + g * 4;   // token base
        const int b2 = m_base >> 11, t = m_base & 2047;
        uint2 ov;
        ov.x = pk_bf16(acc[mb][nb][0] + bvv, acc[mb][nb][1] + bvv);
        ov.y = pk_bf16(acc[mb][nb][2] + bvv, acc[mb][nb][3] + bvv);
        *(uint2*)(vt + ((long)(b2 * NHEAD + hh) * 64 + d) * S_LEN + t) = ov;
      }
    }
  }
}

// ---------------------------------------------------------------------------
// Output projection, m97-style 64x128 tile. 384 blocks, XCD-swizzled.
// A = ctx (bf16), B = w_o (bf16), out fp32. Wave tile 32x64, acc[2][4].
// ---------------------------------------------------------------------------
__global__ __launch_bounds__(256)
void o_kernel(const short* __restrict__ ctx, const short* __restrict__ wo,
              const float* __restrict__ bo, float* __restrict__ out) {
  constexpr int K = 768;
  __shared__ short Abuf[64 * 32];
  __shared__ short Bbuf[128 * 32];

  const int L   = blockIdx.x;        // 0..383
  const int xcd = L & 7;
  const int i   = L >> 3;            // 0..47
  const int nt  = i % 6;
  const int mt  = xcd * 8 + i / 6;   // 0..63
  const int m0  = mt * 64;
  const int n0  = nt * 128;

  const int tid  = threadIdx.x;
  const int lane = tid & 63;
  const int w    = tid >> 6;
  const int g    = lane >> 4;
  const int c    = lane & 15;
  const int wm   = (w & 1) * 32;
  const int wn   = (w >> 1) * 64;

  // A: wave w covers rows [w*16, w*16+16), 1 inst. B: rows [w*32,+32), 2.
  const int arow = w * 16 + (lane >> 2);
  const int brow = w * 32 + (lane >> 2);
  const int dcol = (lane & 3) * 8;
  const short* Ag = ctx + (long)(m0 + arow) * K + dcol;
  const short* Bg = wo + (long)(n0 + brow) * K + dcol;
  short* Al = &Abuf[w * 512];
  short* Bl0 = &Bbuf[w * 1024];
  short* Bl1 = &Bbuf[w * 1024 + 512];

  f32x4 acc[2][4];
#pragma unroll
  for (int a = 0; a < 2; ++a)
#pragma unroll
    for (int b2 = 0; b2 < 4; ++b2) acc[a][b2] = (f32x4){0.f, 0.f, 0.f, 0.f};

  for (int kt = 0; kt < K; kt += 32) {
    lds_dma16(Al, Ag + kt);
    lds_dma16(Bl0, Bg + kt);
    lds_dma16(Bl1, Bg + (long)16 * K + kt);
    __syncthreads();

    s16x8 af[2], bf[4];
#pragma unroll
    for (int mb = 0; mb < 2; ++mb)
      af[mb] = *(const s16x8*)&Abuf[(wm + mb * 16 + c) * 32 + g * 8];
#pragma unroll
    for (int nb = 0; nb < 4; ++nb)
      bf[nb] = *(const s16x8*)&Bbuf[(wn + nb * 16 + c) * 32 + g * 8];
#pragma unroll
    for (int mb = 0; mb < 2; ++mb)
#pragma unroll
      for (int nb = 0; nb < 4; ++nb)
        acc[mb][nb] = MFMA16(af[mb], bf[nb], acc[mb][nb]);
    __syncthreads();
  }

#pragma unroll
  for (int mb = 0; mb < 2; ++mb) {
#pragma unroll
    for (int nb = 0; nb < 4; ++nb) {
      const int n = n0 + wn + nb * 16 + c;
      const float bvv = bo[n];
#pragma unroll
      for (int r = 0; r < 4; ++r) {
        const int m = m0 + wm + mb * 16 + g * 4 + r;
        out[(long)m * DMODEL + n] = acc[mb][nb][r] + bvv;
      }
    }
  }
}

// ---------------------------------------------------------------------------
// Flash attention, no-max softmax. R4: 32x32x16, in-reg P, V direct-to-reg.
//
// 4 waves/block: wave = (rh = w>>1: q-rows rh*32..+32) x (par = w&1: even/odd
// KV tiles). K staged in LDS (XOR swizzle, double parity buffer, shared by
// both rh-waves). V read straight from global into A-fragments:
//   vf{0,1}[sl] = Vt[d = {0,32}+q32][t0 + sl*16 + hi*8]   (16B contiguous)
// prefetched ONE FULL PHASE ahead (issued right after PV consumes the
// previous set) -> ~2700 cyc lead covers L2 latency; each 128B V line is
// fully consumed by 8 lane-accesses of the wave (L1-friendly).
//
// 32x32x16 layouts (A/B: lane&31 = m/n, k = (lane>>5)*8 + j; C/D verified
// m74: col=lane&31, row=(r&3)+8*(r>>2)+4*(lane>>5)):
//   QK: mfma(A=K[t][d], B=Q[d][q]) -> S[t][q];  PV: mfma(A=V[d][t], B=P[t][q]).
//   P built in-register: pk_trunc pairs + v_permlane32_swap_b32 (T12).
// ---------------------------------------------------------------------------
__global__ __launch_bounds__(256, 3)
void attn_kernel(const short* __restrict__ Qh, const short* __restrict__ Kh,
                 const short* __restrict__ Vt, short* __restrict__ Ctx) {
  __shared__ short kbuf[2][64 * 64];      // swizzled K [t][d], per parity
  __shared__ float mbuf[2][64 * 36];      // cross-parity merge, stride 36

  const int tid  = threadIdx.x;
  const int lane = tid & 63;
  const int w    = tid >> 6;
  const int par  = w & 1;                 // tile parity
  const int rh   = w >> 1;                // q-row half
  const int q32  = lane & 31;
  const int hi   = lane >> 5;
  const int bh   = blockIdx.y;            // 0..23
  const int qs0  = blockIdx.x * 64;
  const long base = (long)bh * S_LEN * 64;
  const short* Qb = Qh + base;
  const short* Kb = Kh + base;
  const short* Vb = Vt + base;

  // Q fragments (B operand): n=q32, k=d = db*16 + hi*8 + j
  const long qrow = (long)(qs0 + rh * 32 + q32) * 64;
  s16x8 qf[4];
#pragma unroll
  for (int db = 0; db < 4; ++db)
    qf[db] = *(const s16x8*)(Qb + qrow + db * 16 + hi * 8);

  f32x16 co0, co1;
#pragma unroll
  for (int i = 0; i < 16; ++i) { co0[i] = 0.f; co1[i] = 0.f; }
  float l_lane = 0.f;

  // ---- K staging identities (reg-staged XOR path) ----
  const int srow = tid >> 2;           // 0..63 (t-row)
  const int sq   = tid & 3;
  const int sw   = srow & 7;
  const int sg0  = ((2 * sq)     ^ sw) * 8;
  const int sg1  = ((2 * sq + 1) ^ sw) * 8;
  const short* kg = Kb + (long)srow * 64 + sq * 16;

  uint4 rkE0, rkE1, rkO0, rkO1;
  auto fetch_pair = [&](long tE, long tO) {
    rkE0 = *(const uint4*)(kg + tE * 64);
    rkE1 = *(const uint4*)(kg + tE * 64 + 8);
    rkO0 = *(const uint4*)(kg + tO * 64);
    rkO1 = *(const uint4*)(kg + tO * 64 + 8);
  };
  auto store_pair = [&]() {
    *(uint4*)&kbuf[0][srow * 64 + sg0] = rkE0;
    *(uint4*)&kbuf[0][srow * 64 + sg1] = rkE1;
    *(uint4*)&kbuf[1][srow * 64 + sg0] = rkO0;
    *(uint4*)&kbuf[1][srow * 64 + sg1] = rkO1;
  };

  // ---- V direct-load bases: rows d = q32 and 32+q32 ----
  const short* vrow0 = Vb + (long)q32 * S_LEN + hi * 8;
  const short* vrow1 = vrow0 + (long)32 * S_LEN;
  s16x8 vf0[4], vf1[4];
  auto vload = [&](long t0) {
#pragma unroll
    for (int sl = 0; sl < 4; ++sl) {
      vf0[sl] = *(const s16x8*)(vrow0 + t0 + sl * 16);
      vf1[sl] = *(const s16x8*)(vrow1 + t0 + sl * 16);
    }
  };

  // ---- read-side precomputed offsets ----
  const int tw = lane & 7;
  int c4[4];
#pragma unroll
  for (int i = 0; i < 4; ++i) c4[i] = ((2 * i + hi) ^ tw) * 8;
  const int row0 = q32 * 64;          // Mtile0 (shorts)
  const int row1 = (32 + q32) * 64;   // Mtile1
  const short* kb2 = kbuf[par];

  // P->B-frag builder: words [a', b', c', d'] after two permlane32_swaps.
  auto mkfrag = [&](unsigned a, unsigned b, unsigned c, unsigned d) -> s16x8 {
    asm("v_permlane32_swap_b32 %0, %1" : "+v"(a), "+v"(c));
    asm("v_permlane32_swap_b32 %0, %1" : "+v"(b), "+v"(d));
    uint4 u;
    u.x = a; u.y = b; u.z = c; u.w = d;
    return __builtin_bit_cast(s16x8, u);
  };

  // step on this wave's parity tile; issues V prefetch for tile at tv_next.
  auto step = [&](long tv_next) {
    // QK^T: S[t][q], t split in two 32-row Mtiles
    f32x16 s0, s1;
#pragma unroll
    for (int i = 0; i < 16; ++i) { s0[i] = 0.f; s1[i] = 0.f; }
    __builtin_amdgcn_s_setprio(1);
#pragma unroll
    for (int db = 0; db < 4; ++db) {
      const s16x8 k0 = *(const s16x8*)&kb2[row0 + c4[db]];
      const s16x8 k1 = *(const s16x8*)&kb2[row1 + c4[db]];
      s0 = MFMA32(k0, qf[db], s0);
      s1 = MFMA32(k1, qf[db], s1);
    }
    __builtin_amdgcn_s_setprio(0);
    // exp2 + l + pack (pairs are t-consecutive: regs (2i, 2i+1))
    unsigned pk0[8], pk1[8];
    float la = 0.f, lb = 0.f;
#pragma unroll
    for (int i = 0; i < 8; ++i) {
      float a0 = __builtin_amdgcn_exp2f(s0[2 * i]);
      float b0 = __builtin_amdgcn_exp2f(s0[2 * i + 1]);
      float a1 = __builtin_amdgcn_exp2f(s1[2 * i]);
      float b1 = __builtin_amdgcn_exp2f(s1[2 * i + 1]);
      la += bf16_floor(a0) + bf16_floor(b0);
      lb += bf16_floor(a1) + bf16_floor(b1);
      pk0[i] = pk_trunc(a0, b0);
      pk1[i] = pk_trunc(a1, b1);
    }
    l_lane += la + lb;
    // B-frags: slice0 t0..15 (pk0[0..3]), slice1 t16..31 (pk0[4..7]),
    //          slice2 t32..47 (pk1[0..3]), slice3 t48..63 (pk1[4..7])
    s16x8 pf0 = mkfrag(pk0[0], pk0[1], pk0[2], pk0[3]);
    s16x8 pf1 = mkfrag(pk0[4], pk0[5], pk0[6], pk0[7]);
    s16x8 pf2 = mkfrag(pk1[0], pk1[1], pk1[2], pk1[3]);
    s16x8 pf3 = mkfrag(pk1[4], pk1[5], pk1[6], pk1[7]);
    // PV: co[d][q] += V[d][t] * P[t][q]  (consumes vf -> then refill)
    __builtin_amdgcn_s_setprio(1);
    co0 = MFMA32(vf0[0], pf0, co0);
    co1 = MFMA32(vf1[0], pf0, co1);
    co0 = MFMA32(vf0[1], pf1, co0);
    co1 = MFMA32(vf1[1], pf1, co1);
    co0 = MFMA32(vf0[2], pf2, co0);
    co1 = MFMA32(vf1[2], pf2, co1);
    co0 = MFMA32(vf0[3], pf3, co0);
    co1 = MFMA32(vf1[3], pf3, co1);
    __builtin_amdgcn_s_setprio(0);
    vload(tv_next);   // prefetch next parity tile's V (one full phase ahead)
  };

  constexpr int NT = S_LEN / 64;   // 32 tiles, 16 phases
  fetch_pair(0, 64);
  store_pair();
  vload((long)par * 64);           // V for this wave's first tile
  for (int ph = 0; ph < NT / 2; ++ph) {
    __syncthreads();                               // both K buffers ready
    const long tE = (2 * ph + 2 < NT) ? (long)(2 * ph + 2) * 64 : 0;
    const long tO = (2 * ph + 3 < NT) ? (long)(2 * ph + 3) * 64 : 0;
    fetch_pair(tE, tO);                            // K regs for next pair
    const long tv = (2 * ph + 2 + par < NT) ? (long)(2 * ph + 2 + par) * 64 : 0;
    step(tv);                                      // wave's parity tile
    __syncthreads();                               // all done reading kbuf
    store_pair();                                  // refill both K buffers
  }

  // l: combine the two t-half lanes (same q) of this wave's tiles
  float rs = l_lane + __shfl_xor(l_lane, 32);

  // ---- cross-parity merge via LDS (stride 36 floats = 144B, 16B-aligned) ----
  __syncthreads();
  float* mp = mbuf[rh] + lane * 36;
  if (par) {
#pragma unroll
    for (int i = 0; i < 4; ++i) {
      *(float4*)(mp + 4 * i)      = make_float4(co0[4*i], co0[4*i+1], co0[4*i+2], co0[4*i+3]);
      *(float4*)(mp + 16 + 4 * i) = make_float4(co1[4*i], co1[4*i+1], co1[4*i+2], co1[4*i+3]);
    }
    mp[32] = rs;
  }
  __syncthreads();
  if (!par) {
#pragma unroll
    for (int i = 0; i < 4; ++i) {
      float4 a = *(const float4*)(mp + 4 * i);
      float4 b = *(const float4*)(mp + 16 + 4 * i);
      co0[4*i] += a.x; co0[4*i+1] += a.y; co0[4*i+2] += a.z; co0[4*i+3] += a.w;
      co1[4*i] += b.x; co1[4*i+1] += b.y; co1[4*i+2] += b.z; co1[4*i+3] += b.w;
    }
    rs += mp[32];
    const float invl = 1.f / rs;

    const int hh = bh % NHEAD;
    const long tok = (long)(bh / NHEAD) * S_LEN + qs0 + rh * 32 + q32;
    short* outp = Ctx + tok * DMODEL + hh * 64;
    // reg r -> d = (r&3) + 8*(r>>2) + 4*hi (+32 for co1)
#pragma unroll
    for (int rq = 0; rq < 4; ++rq) {
      const int d0 = 8 * rq + 4 * hi;
      uint2 ov;
      ov.x = pk_bf16(co0[4*rq] * invl, co0[4*rq+1] * invl);
      ov.y = pk_bf16(co0[4*rq+2] * invl, co0[4*rq+3] * invl);
      *(uint2*)(outp + d0) = ov;
      uint2 ov2;
      ov2.x = pk_bf16(co1[4*rq] * invl, co1[4*rq+1] * invl);
      ov2.y = pk_bf16(co1[4*rq+2] * invl, co1[4*rq+3] * invl);
      *(uint2*)(outp + 32 + d0) = ov2;
    }
  }
}

// ---------------------------------------------------------------------------
extern "C" void kernel_launch(void* const* d_in, const int* in_sizes, int n_in,
                              void* d_out, int out_size, void* d_ws, size_t ws_size,
                              hipStream_t stream) {
  const float* q   = (const float*)d_in[0];
  const float* k   = (const float*)d_in[1];
  const float* v   = (const float*)d_in[2];
  const float* w_q = (const float*)d_in[3];
  const float* b_q = (const float*)d_in[4];
  const float* w_k = (const float*)d_in[5];
  const float* b_k = (const float*)d_in[6];
  const float* w_v = (const float*)d_in[7];
  const float* b_v = (const float*)d_in[8];
  const float* w_o = (const float*)d_in[9];
  const float* b_o = (const float*)d_in[10];
  float* out = (float*)d_out;

  const long NELEM = (long)2 * NHEAD * S_LEN * 64;  // 3,145,728
  const long WELEM = (long)DMODEL * DMODEL;         // 589,824
  short* qh  = (short*)d_ws;
  short* kh  = qh + NELEM;
  short* vt  = kh + NELEM;
  short* wqb = vt + NELEM;
  short* wkb = wqb + WELEM;
  short* wvb = wkb + WELEM;
  short* wob = wvb + WELEM;
  short* qb  = wob + WELEM;
  short* kb  = qb + NELEM;
  short* vb  = kb + NELEM;
  short* ctx = qb;   // alias: qb dead after qkv_kernel; attn writes ctx after

  dim3 blk(256);
  convert_all<<<dim3(11520), blk, 0, stream>>>(q, k, v, w_q, w_k, w_v, w_o,
                                               qb, kb, vb, wqb, wkb, wvb, wob);
  qkv_kernel<<<dim3(576), blk, 0, stream>>>(qb, kb, vb, wqb, wkb, wvb,
                                            b_q, b_k, b_v, qh, kh, vt);
  attn_kernel<<<dim3(32, 24), blk, 0, stream>>>(qh, kh, vt, ctx);
  o_kernel<<<dim3(384), blk, 0, stream>>>(ctx, wob, b_o, out);
}